// Round 10
// baseline (215.734 us; speedup 1.0000x reference)
//
#include <hip/hip_runtime.h>
#include <hip/hip_bf16.h>

#define N_NODES 100000
#define N_EDGES 1250000
#define HID 64
#define LDSS 72       // LDS row stride in bf16 elems: 64 + 8 pad (144 B rows)
#define NB 196        // buckets of 512 node-ids: (100000+511)/512
#define NBLOCK 128    // edge-slice blocks for hist/P3
#define EMB_BLOCKS 6250  // N_NODES*16/256 exactly

typedef __bf16 bf16x8 __attribute__((ext_vector_type(8)));
typedef float  f32x4  __attribute__((ext_vector_type(4)));

__device__ __forceinline__ float bflo(uint u) {   // low bf16 of packed uint -> f32
    union { unsigned int i; float f; } v; v.i = u << 16; return v.f;
}
__device__ __forceinline__ float bfhi(uint u) {   // high bf16 -> f32
    union { unsigned int i; float f; } v; v.i = u & 0xFFFF0000u; return v.f;
}
__device__ __forceinline__ ushort f2bf(float f) {
    union { float f; unsigned int i; } v; v.f = f;
    unsigned int x = v.i;
    return (ushort)((x + 0x7fffu + ((x >> 16) & 1u)) >> 16);  // RNE
}

// Edge histogram into 196 coarse buckets (dst>>9), per-slice counts to gh.
__global__ __launch_bounds__(256) void hist_k(const int* __restrict__ dst,
                                              int* __restrict__ gh) {
    __shared__ int hist[NB];
    const int tid = threadIdx.x;
    for (int i = tid; i < NB; i += 256) hist[i] = 0;
    __syncthreads();
    const int4* d4 = (const int4*)dst;                // N_EDGES % 4 == 0
    for (int e = blockIdx.x * 256 + tid; e < N_EDGES / 4; e += NBLOCK * 256) {
        int4 v = d4[e];
        atomicAdd(&hist[v.x >> 9], 1);
        atomicAdd(&hist[v.y >> 9], 1);
        atomicAdd(&hist[v.z >> 9], 1);
        atomicAdd(&hist[v.w >> 9], 1);
    }
    __syncthreads();
    for (int i = tid; i < NB; i += 256) gh[blockIdx.x * NB + i] = hist[i];
}

// Fused: blocks [0,128) p3-scatter (needs gh), [128,6378) embed-gather,
// [6378,6383) weight convert. embed/wcvt are independent of p3 -> overlap;
// p3 blocks dispatched first so p4's dependency clears earliest.
__global__ __launch_bounds__(256) void work2(const int* __restrict__ x,
                                             const float* __restrict__ emb,
                                             ushort* __restrict__ h0,
                                             const int* __restrict__ src,
                                             const int* __restrict__ dst,
                                             const int* __restrict__ gh,
                                             int* __restrict__ bstart,
                                             uint* __restrict__ ebuf,
                                             const float* __restrict__ Wl1,
                                             const float* __restrict__ Wr1,
                                             const float* __restrict__ Wl2,
                                             const float* __restrict__ Wr2,
                                             const float* __restrict__ Wout,
                                             ushort* __restrict__ wbf) {
    const int b = blockIdx.x;
    const int tid = threadIdx.x;
    if (b < NBLOCK) {
        // ---- p3 scatter: per-block recompute of column-prefix + bucket scan
        __shared__ int base[NB];
        __shared__ int run[NB];
        __shared__ int wsum[4];
        const int lane = tid & 63, wave = tid >> 6;
        int myTot = 0, myPre = 0;
        if (tid < NB) {
#pragma unroll 8
            for (int bb = 0; bb < NBLOCK; ++bb) {
                int c = gh[bb * NB + tid];
                if (bb == b) myPre = myTot;
                myTot += c;
            }
        }
        int x2 = myTot;
#pragma unroll
        for (int d = 1; d < 64; d <<= 1) {
            int y = __shfl_up(x2, d, 64);
            if (lane >= d) x2 += y;
        }
        if (lane == 63) wsum[wave] = x2;
        __syncthreads();
        if (wave == 0) {
            int s = (lane < 4) ? wsum[lane] : 0;
#pragma unroll
            for (int d = 1; d < 4; d <<= 1) {
                int y = __shfl_up(s, d, 64);
                if (lane >= d) s += y;
            }
            if (lane < 4) wsum[lane] = s;
        }
        __syncthreads();
        int waveoff = (wave == 0) ? 0 : wsum[wave - 1];
        int excl = waveoff + (x2 - myTot);
        if (tid < NB) {
            base[tid] = excl + myPre;
            run[tid] = 0;
            if (b == 0) bstart[tid] = excl;
        }
        if (b == 0 && tid == 0) bstart[NB] = N_EDGES;
        __syncthreads();
        const int4* s4 = (const int4*)src;
        const int4* d4 = (const int4*)dst;
        for (int e = b * 256 + tid; e < N_EDGES / 4; e += NBLOCK * 256) {
            int4 dv = d4[e];
            int4 sv = s4[e];
            int b0 = dv.x >> 9;
            int r0 = atomicAdd(&run[b0], 1);
            ebuf[base[b0] + r0] = ((uint)(dv.x & 511) << 17) | (uint)sv.x;
            int b1 = dv.y >> 9;
            int r1 = atomicAdd(&run[b1], 1);
            ebuf[base[b1] + r1] = ((uint)(dv.y & 511) << 17) | (uint)sv.y;
            int b2 = dv.z >> 9;
            int r2 = atomicAdd(&run[b2], 1);
            ebuf[base[b2] + r2] = ((uint)(dv.z & 511) << 17) | (uint)sv.z;
            int b3 = dv.w >> 9;
            int r3 = atomicAdd(&run[b3], 1);
            ebuf[base[b3] + r3] = ((uint)(dv.w & 511) << 17) | (uint)sv.w;
        }
    } else if (b < NBLOCK + EMB_BLOCKS) {
        // ---- embed gather: h0[i][:] = bf16(emb[x[i]][:])
        int t = (b - NBLOCK) * 256 + tid;
        int row = t >> 4, c = t & 15;
        int idx = x[row];
        float4 v = ((const float4*)(emb + (size_t)idx * HID))[c];
        ushort4 w;
        w.x = f2bf(v.x); w.y = f2bf(v.y); w.z = f2bf(v.z); w.w = f2bf(v.w);
        ((ushort4*)(h0 + (size_t)row * HID))[c] = w;
    } else {
        const int wb = b - NBLOCK - EMB_BLOCKS;
        const float* W = (wb == 0) ? Wl1 : (wb == 1) ? Wr1 :
                         (wb == 2) ? Wl2 : (wb == 3) ? Wr2 : Wout;
        ushort* o = wbf + wb * 4096;
        for (int idx = tid; idx < 4096; idx += 256) {
            int k = idx >> 6, n = idx & 63;
            o[n * 64 + k] = f2bf(W[idx]);   // wbf[m][n*64+k] = bf16(W[k][n])
        }
    }
}

__global__ __launch_bounds__(256) void p4_csr(const uint* __restrict__ ebuf,
                                              const int* __restrict__ bstart,
                                              int* __restrict__ rowptr,
                                              int* __restrict__ csr_src) {
    __shared__ int hist[512], hoff[512], run[512];
    __shared__ int wsum[4];
    const int v = blockIdx.x;
    const int tid = threadIdx.x, lane = tid & 63, wave = tid >> 6;
    const int node0 = v << 9;
    const int nn = min(512, N_NODES - node0);
    const int beg = bstart[v], end = bstart[v + 1];

    for (int i = tid; i < 512; i += 256) { hist[i] = 0; run[i] = 0; }
    __syncthreads();
    for (int e = beg + tid; e < end; e += 256)
        atomicAdd(&hist[ebuf[e] >> 17], 1);
    __syncthreads();
    int h0 = hist[2 * tid], h1 = hist[2 * tid + 1];
    int s = h0 + h1;
    int x = s;
#pragma unroll
    for (int d = 1; d < 64; d <<= 1) {
        int y = __shfl_up(x, d, 64);
        if (lane >= d) x += y;
    }
    if (lane == 63) wsum[wave] = x;
    __syncthreads();
    if (wave == 0) {
        int s2 = (lane < 4) ? wsum[lane] : 0;
#pragma unroll
        for (int d = 1; d < 4; d <<= 1) {
            int y = __shfl_up(s2, d, 64);
            if (lane >= d) s2 += y;
        }
        if (lane < 4) wsum[lane] = s2;
    }
    __syncthreads();
    int waveoff = (wave == 0) ? 0 : wsum[wave - 1];
    int excl = waveoff + (x - s);
    hoff[2 * tid] = excl;
    hoff[2 * tid + 1] = excl + h0;
    __syncthreads();
    for (int j = tid; j < nn; j += 256) rowptr[node0 + j] = beg + hoff[j];
    if (v == NB - 1 && tid == 0) rowptr[N_NODES] = N_EDGES;
    for (int e = beg + tid; e < end; e += 256) {
        uint p = ebuf[e];
        int dl = p >> 17;
        int r = atomicAdd(&run[dl], 1);
        csr_src[beg + hoff[dl] + r] = (int)(p & 0x1FFFFu);
    }
}

#define ACCUM(wa, wb)                                                      \
    a0 += bflo(wa.x); a1 += bfhi(wa.x); a2 += bflo(wa.y); a3 += bfhi(wa.y); \
    a4 += bflo(wa.z); a5 += bfhi(wa.z); a6 += bflo(wa.w); a7 += bfhi(wa.w); \
    a8 += bflo(wb.x); a9 += bfhi(wb.x); a10 += bflo(wb.y); a11 += bfhi(wb.y); \
    a12 += bflo(wb.z); a13 += bfhi(wb.z); a14 += bflo(wb.w); a15 += bfhi(wb.w);

#define GATHER(j)                                                          \
    const uint4* p##j = (const uint4*)&hin[(size_t)s##j * HID + q * 16];   \
    uint4 A##j = p##j[0], B##j = p##j[1];

#define SHXOR(OFF)                                                          \
    a0 += __shfl_xor(a0, OFF, 64);   a1 += __shfl_xor(a1, OFF, 64);         \
    a2 += __shfl_xor(a2, OFF, 64);   a3 += __shfl_xor(a3, OFF, 64);         \
    a4 += __shfl_xor(a4, OFF, 64);   a5 += __shfl_xor(a5, OFF, 64);         \
    a6 += __shfl_xor(a6, OFF, 64);   a7 += __shfl_xor(a7, OFF, 64);         \
    a8 += __shfl_xor(a8, OFF, 64);   a9 += __shfl_xor(a9, OFF, 64);         \
    a10 += __shfl_xor(a10, OFF, 64); a11 += __shfl_xor(a11, OFF, 64);       \
    a12 += __shfl_xor(a12, OFF, 64); a13 += __shfl_xor(a13, OFF, 64);       \
    a14 += __shfl_xor(a14, OFF, 64); a15 += __shfl_xor(a15, OFF, 64);

// Fused layer: 16-lane/node QUARTER-split aggregation + MFMA GEMM.
//  - 256 threads, 16 nodes/block (6250 blocks exact). Node nl = tid>>4;
//    lane bits: hh = (tid>>2)&3 edge-quarter, q = tid&3 dim-piece (16 dims).
//  - quarter-degree ~3.1 -> P(quarter<=8) ~99.6%: the TYPICAL wave runs ONE
//    masked batch-8 exposure (r9's half-split ran ~2). Clamped slots load
//    duplicate addresses (coalesced ~free); ACCUM of zeros costs VALU only
//    (31% busy in r9 -> headroom).
//  - combine quarters with 2 shfl_xor levels (4 then 8); hh==0 writes sA.
//  - one __syncthreads, then wave 0 runs the proven MFMA/epilogue for the
//    block's 16 rows; waves 1-3 retire.
//  - weights + hin A-fragments read directly from global (L2-hot).
template <bool OUTPROJ>
__global__ __launch_bounds__(256, 4) void layer_fused(
    const int* __restrict__ rowptr, const int* __restrict__ csr_src,
    const ushort* __restrict__ hin,
    const ushort* __restrict__ wl_bf, const float* __restrict__ bl,
    const ushort* __restrict__ wr_bf, const float* __restrict__ alpha_p,
    const ushort* __restrict__ wo_bf, const float* __restrict__ bo,
    void* __restrict__ out_p) {
    __shared__ __align__(16) ushort sA[16][LDSS];      // 2304 B

    const int tid = threadIdx.x;
    const int row0 = blockIdx.x * 16;
    const int wave = tid >> 6, lane = tid & 63;

    // ---- aggregation: 16 lanes/node; hh = edge quarter, q = dim piece
    const int nl = tid >> 4, hh = (tid >> 2) & 3, q = tid & 3;
    {
        const int node = row0 + nl;                    // < N_NODES always
        const int beg = rowptr[node], end = rowptr[node + 1];
        const int d = end - beg;
        const int hbeg = beg + ((d * hh) >> 2);
        const int hend = beg + ((d * (hh + 1)) >> 2);
        float a0 = 0.f, a1 = 0.f, a2 = 0.f, a3 = 0.f;
        float a4 = 0.f, a5 = 0.f, a6 = 0.f, a7 = 0.f;
        float a8 = 0.f, a9 = 0.f, a10 = 0.f, a11 = 0.f;
        float a12 = 0.f, a13 = 0.f, a14 = 0.f, a15 = 0.f;
        int i = hbeg;
        for (; i + 8 <= hend; i += 8) {
            int s0 = csr_src[i + 0], s1 = csr_src[i + 1];
            int s2 = csr_src[i + 2], s3 = csr_src[i + 3];
            int s4 = csr_src[i + 4], s5 = csr_src[i + 5];
            int s6 = csr_src[i + 6], s7 = csr_src[i + 7];
            GATHER(0) GATHER(1) GATHER(2) GATHER(3)
            GATHER(4) GATHER(5) GATHER(6) GATHER(7)
            ACCUM(A0, B0) ACCUM(A1, B1) ACCUM(A2, B2) ACCUM(A3, B3)
            ACCUM(A4, B4) ACCUM(A5, B5) ACCUM(A6, B6) ACCUM(A7, B7)
        }
        if (i < hend) {     // masked batch-8 tail: clamp idx, zero invalid
            const int e1 = hend - 1;
            int s0 = csr_src[i + 0];
            int s1 = csr_src[(i + 1 <= e1) ? i + 1 : e1];
            int s2 = csr_src[(i + 2 <= e1) ? i + 2 : e1];
            int s3 = csr_src[(i + 3 <= e1) ? i + 3 : e1];
            int s4 = csr_src[(i + 4 <= e1) ? i + 4 : e1];
            int s5 = csr_src[(i + 5 <= e1) ? i + 5 : e1];
            int s6 = csr_src[(i + 6 <= e1) ? i + 6 : e1];
            int s7 = csr_src[(i + 7 <= e1) ? i + 7 : e1];
            GATHER(0) GATHER(1) GATHER(2) GATHER(3)
            GATHER(4) GATHER(5) GATHER(6) GATHER(7)
            const uint4 z = {0, 0, 0, 0};
            if (i + 1 > e1) { A1 = z; B1 = z; }
            if (i + 2 > e1) { A2 = z; B2 = z; }
            if (i + 3 > e1) { A3 = z; B3 = z; }
            if (i + 4 > e1) { A4 = z; B4 = z; }
            if (i + 5 > e1) { A5 = z; B5 = z; }
            if (i + 6 > e1) { A6 = z; B6 = z; }
            if (i + 7 > e1) { A7 = z; B7 = z; }
            ACCUM(A0, B0) ACCUM(A1, B1) ACCUM(A2, B2) ACCUM(A3, B3)
            ACCUM(A4, B4) ACCUM(A5, B5) ACCUM(A6, B6) ACCUM(A7, B7)
        }
        // combine the 4 quarters (lane bits 2-3)
        SHXOR(4)
        SHXOR(8)
        if (hh == 0) {
            float inv = (d > 0) ? 1.0f / (float)d : 0.f;
            uint4 o0, o1;
            o0.x = (uint)f2bf(a0 * inv)  | ((uint)f2bf(a1 * inv) << 16);
            o0.y = (uint)f2bf(a2 * inv)  | ((uint)f2bf(a3 * inv) << 16);
            o0.z = (uint)f2bf(a4 * inv)  | ((uint)f2bf(a5 * inv) << 16);
            o0.w = (uint)f2bf(a6 * inv)  | ((uint)f2bf(a7 * inv) << 16);
            o1.x = (uint)f2bf(a8 * inv)  | ((uint)f2bf(a9 * inv) << 16);
            o1.y = (uint)f2bf(a10 * inv) | ((uint)f2bf(a11 * inv) << 16);
            o1.z = (uint)f2bf(a12 * inv) | ((uint)f2bf(a13 * inv) << 16);
            o1.w = (uint)f2bf(a14 * inv) | ((uint)f2bf(a15 * inv) << 16);
            *(uint4*)&sA[nl][q * 16] = o0;
            *(uint4*)&sA[nl][q * 16 + 8] = o1;
        }
    }
    __syncthreads();
    if (wave >= 1) return;          // waves 1-3 done (no further barriers)

    // ---- MFMA: wave 0 owns the block's 16 rows; B-frags straight from global
    const int quad = lane >> 4, lr = lane & 15;
    const int grow = row0 + lr;
    const float alpha = alpha_p[0];

    bf16x8 hf[2], af[2];
#pragma unroll
    for (int ks = 0; ks < 2; ++ks) {
        int k0 = ks * 32 + quad * 8;
        uint4 hv = *(const uint4*)&hin[(size_t)grow * HID + k0];
        hf[ks] = __builtin_bit_cast(bf16x8, hv);
        uint4 av = *(const uint4*)&sA[lr][k0];
        af[ks] = __builtin_bit_cast(bf16x8, av);
    }

    f32x4 acc[4];
#pragma unroll
    for (int nt = 0; nt < 4; ++nt) {
        f32x4 a = {0.f, 0.f, 0.f, 0.f};
#pragma unroll
        for (int ks = 0; ks < 2; ++ks) {
            int k0 = ks * 32 + quad * 8;
            bf16x8 wr = *(const bf16x8*)&wr_bf[(nt * 16 + lr) * 64 + k0];
            a = __builtin_amdgcn_mfma_f32_16x16x32_bf16(hf[ks], wr, a, 0, 0, 0);
            bf16x8 wl = *(const bf16x8*)&wl_bf[(nt * 16 + lr) * 64 + k0];
            a = __builtin_amdgcn_mfma_f32_16x16x32_bf16(af[ks], wl, a, 0, 0, 0);
        }
        acc[nt] = a;
    }

    if constexpr (!OUTPROJ) {
        // PReLU result -> sA, then packed uint4 stores (wave-private rows)
#pragma unroll
        for (int nt = 0; nt < 4; ++nt) {
            int col = nt * 16 + lr;
            float bias = bl[col];
#pragma unroll
            for (int r = 0; r < 4; ++r) {
                int row = quad * 4 + r;   // C/D: col=lane&15, row=(lane>>4)*4+reg
                float v = acc[nt][r] + bias;
                v = (v >= 0.f) ? v : alpha * v;
                sA[row][col] = f2bf(v);
            }
        }
        ushort* outp = (ushort*)out_p;
        const int lrow = lane >> 3, lch = lane & 7;  // 8 rows x 8 chunks per pass
#pragma unroll
        for (int pass = 0; pass < 2; ++pass) {
            int row = pass * 8 + lrow;
            int gg2 = row0 + row;
            uint4 v4 = *(const uint4*)&sA[row][lch * 8];
            *(uint4*)&outp[(size_t)gg2 * HID + lch * 8] = v4;
        }
    } else {
        // h2 (post-PReLU bf16) -> sA, then @Wout + bout, f32 out
#pragma unroll
        for (int nt = 0; nt < 4; ++nt) {
            int col = nt * 16 + lr;
            float bias = bl[col];
#pragma unroll
            for (int r = 0; r < 4; ++r) {
                int row = quad * 4 + r;
                float v = acc[nt][r] + bias;
                v = (v >= 0.f) ? v : alpha * v;
                sA[row][col] = f2bf(v);
            }
        }
        bf16x8 h2f[2];
#pragma unroll
        for (int ks = 0; ks < 2; ++ks) {
            int k0 = ks * 32 + quad * 8;
            uint4 hv = *(const uint4*)&sA[lr][k0];
            h2f[ks] = __builtin_bit_cast(bf16x8, hv);
        }
        f32x4 acc2[4];
#pragma unroll
        for (int nt = 0; nt < 4; ++nt) {
            f32x4 a = {0.f, 0.f, 0.f, 0.f};
#pragma unroll
            for (int ks = 0; ks < 2; ++ks) {
                int k0 = ks * 32 + quad * 8;
                bf16x8 wo = *(const bf16x8*)&wo_bf[(nt * 16 + lr) * 64 + k0];
                a = __builtin_amdgcn_mfma_f32_16x16x32_bf16(h2f[ks], wo, a, 0, 0, 0);
            }
            acc2[nt] = a;
        }
        float* outp = (float*)out_p;
#pragma unroll
        for (int nt = 0; nt < 4; ++nt) {
            int col = nt * 16 + lr;
            float bias = bo[col];
#pragma unroll
            for (int r = 0; r < 4; ++r) {
                int row = quad * 4 + r;
                int gg2 = row0 + row;
                outp[(size_t)gg2 * HID + col] = acc2[nt][r] + bias;
            }
        }
    }
}

extern "C" void kernel_launch(void* const* d_in, const int* in_sizes, int n_in,
                              void* d_out, int out_size, void* d_ws, size_t ws_size,
                              hipStream_t stream) {
    const int*   x    = (const int*)d_in[0];
    const int*   src  = (const int*)d_in[1];
    const int*   dst  = src + N_EDGES;
    const float* emb  = (const float*)d_in[3];
    const float* Wl1  = (const float*)d_in[4];
    const float* bl1  = (const float*)d_in[5];
    const float* Wr1  = (const float*)d_in[6];
    const float* a1   = (const float*)d_in[7];
    const float* Wl2  = (const float*)d_in[8];
    const float* bl2  = (const float*)d_in[9];
    const float* Wr2  = (const float*)d_in[10];
    const float* a2   = (const float*)d_in[11];
    const float* Wout = (const float*)d_in[12];
    const float* bout = (const float*)d_in[13];

    char* ws = (char*)d_ws;
    int*    gh      = (int*)ws;                      // 100,352 (pad 100,416)
    int*    bstart  = (int*)(ws + 101248);           // 832
    int*    rowptr  = (int*)(ws + 102080);           // 400,064
    ushort* wbf     = (ushort*)(ws + 502144);        // 40,960
    uint*   ebuf    = (uint*)(ws + 543104);          // 5,000,000
    int*    csr_src = (int*)(ws + 5543104);          // 5,000,000
    ushort* h0      = (ushort*)(ws + 10543104);      // 12.8 MB
    ushort* h1      = (ushort*)(ws + 23343104);      // 12.8 MB

    ushort* wl1b  = wbf;
    ushort* wr1b  = wbf + 4096;
    ushort* wl2b  = wbf + 8192;
    ushort* wr2b  = wbf + 12288;
    ushort* woutb = wbf + 16384;

    const int layer_blocks = N_NODES / 16;           // 6250 (exact)

    hist_k<<<NBLOCK, 256, 0, stream>>>(dst, gh);
    work2<<<NBLOCK + EMB_BLOCKS + 5, 256, 0, stream>>>(
        x, emb, h0, src, dst, gh, bstart, ebuf, Wl1, Wr1, Wl2, Wr2, Wout, wbf);
    p4_csr<<<NB, 256, 0, stream>>>(ebuf, bstart, rowptr, csr_src);

    layer_fused<false><<<layer_blocks, 256, 0, stream>>>(
        rowptr, csr_src, h0, wl1b, bl1, wr1b, a1, wr1b, bl1, h1);
    layer_fused<true><<<layer_blocks, 256, 0, stream>>>(
        rowptr, csr_src, h1, wl2b, bl2, wr2b, a2, woutb, bout, d_out);
}